// Round 13
// baseline (197.450 us; speedup 1.0000x reference)
//
#include <hip/hip_runtime.h>
#include <hip/hip_bf16.h>
#include <math.h>

#define BATCH 8
#define SEQ 384
#define DIM 768
#define NH 12
#define DH 64
#define NPOS 767
#define POS_OFF 128
#define NTOK (BATCH * SEQ)
#define QKN 1536
#define QKVN 2304
#define PN 1536

typedef __attribute__((ext_vector_type(8))) short short8;
typedef __attribute__((ext_vector_type(4))) float floatx4;
typedef unsigned int u32;

__device__ __forceinline__ ushort f2bf(float f) {
    __hip_bfloat16 h = __float2bfloat16(f);
    return *reinterpret_cast<ushort*>(&h);
}
__device__ __forceinline__ float bf2f(ushort u) {
    u32 x = ((u32)u) << 16;
    float f; __builtin_memcpy(&f, &x, 4); return f;
}

// async global->LDS, 16B per lane; lds dest = wave-uniform base + lane*16
__device__ __forceinline__ void gld16(const ushort* g, ushort* l) {
    __builtin_amdgcn_global_load_lds(
        (const __attribute__((address_space(1))) u32*)g,
        (__attribute__((address_space(3))) u32*)l, 16, 0, 0);
}

#define MFMA __builtin_amdgcn_mfma_f32_16x16x32_bf16

// ---------- prep: weight transposes (z<6) + row converts (z==6) -----------
__global__ __launch_bounds__(256) void prep(
    const float* W0, const float* W1, const float* W2,
    const float* W3, const float* W4, const float* W5,
    const float* x, const float* rpe,
    ushort* __restrict__ wsT, ushort* __restrict__ xb, ushort* __restrict__ rpeb)
{
    const int tid = threadIdx.x;
    if (blockIdx.z < 6) {
        __shared__ float t[64][65];
        const float* srcs[6] = {W0, W1, W2, W3, W4, W5};
        const float* in = srcs[blockIdx.z];
        ushort* out = wsT + (size_t)blockIdx.z * DIM * DIM;
        const int r0 = blockIdx.y * 64, c0 = blockIdx.x * 64;
        for (int p = 0; p < 16; ++p) {
            int e = tid + p * 256, i = e >> 6, j = e & 63;
            t[i][j] = in[(size_t)(r0 + i) * DIM + c0 + j];
        }
        __syncthreads();
        for (int p = 0; p < 16; ++p) {
            int e = tid + p * 256, i = e >> 6, j = e & 63;
            out[(size_t)(c0 + i) * DIM + r0 + j] = f2bf(t[j][i]);
        }
    } else {
        const int n4x = NTOK * DIM / 4;
        const int n4p = NPOS * DIM / 4;
        const int fb = blockIdx.y * 12 + blockIdx.x;      // 0..143
        for (int idx = fb * 256 + tid; idx < n4x + n4p; idx += 144 * 256) {
            const float* src; ushort* dst; int j;
            if (idx < n4x) { src = x; dst = xb; j = idx; }
            else { src = rpe + (size_t)POS_OFF * DIM; dst = rpeb; j = idx - n4x; }
            float4 f = ((const float4*)src)[j];
            ushort o[4] = {f2bf(f.x), f2bf(f.y), f2bf(f.z), f2bf(f.w)};
            *(uint2*)&dst[(size_t)j * 4] = *(uint2*)o;
        }
    }
}

// ---------- combined projections: QKV (blocks 0..431) + pos (432..503) ----
__global__ __launch_bounds__(256) void proj_all(
    const ushort* __restrict__ xb, const ushort* __restrict__ rpeb,
    const ushort* __restrict__ wsT,
    const float* __restrict__ bq, const float* __restrict__ qbias,
    const float* __restrict__ bk, const float* __restrict__ bv,
    const float* __restrict__ vbias,
    ushort* __restrict__ qk, ushort* __restrict__ vT, ushort* __restrict__ posKQ)
{
    __shared__ ushort As[128 * 64];
    __shared__ ushort Bs[128 * 64];
    const int tid = threadIdx.x;
    const int lane = tid & 63, w = tid >> 6;
    const int id = blockIdx.x;
    const bool qkvP = id < 432;
    const ushort* A; const ushort* Bt; int m0, n0, M;
    if (qkvP) {
        m0 = (id % 24) * 128; n0 = (id / 24) * 128;
        A = xb; Bt = wsT; M = NTOK;
    } else {
        int p = id - 432;
        m0 = (p % 6) * 128; n0 = (p / 6) * 128;
        A = rpeb; Bt = wsT + (size_t)3 * DIM * DIM; M = NPOS;
    }
    const int lr = lane >> 3;
    const int lc = (lane & 7) ^ (lr & 7);
    const ushort* ga[4]; const ushort* gb[4];
#pragma unroll
    for (int p = 0; p < 4; ++p) {
        int row = (w * 4 + p) * 8 + lr;
        int arow = m0 + row; if (arow > M - 1) arow = M - 1;
        ga[p] = A + (size_t)arow * DIM + lc * 8;
        gb[p] = Bt + (size_t)(n0 + row) * DIM + lc * 8;
    }
    floatx4 acc[4][4] = {};
    const int qr = (w >> 1) * 64, qc = (w & 1) * 64;
    const int lm = lane & 15, lk = lane >> 4;
    for (int k0 = 0; k0 < DIM; k0 += 64) {
#pragma unroll
        for (int p = 0; p < 4; ++p) {
            gld16(ga[p], As + (w * 4 + p) * 512);
            gld16(gb[p], Bs + (w * 4 + p) * 512);
            ga[p] += 64; gb[p] += 64;
        }
        __syncthreads();
#pragma unroll
        for (int kk = 0; kk < 2; ++kk) {
            int ch = (kk * 4 + lk) ^ (lm & 7);
            short8 af[4], bf[4];
#pragma unroll
            for (int t = 0; t < 4; ++t) {
                af[t] = *(const short8*)&As[(qr + t * 16 + lm) * 64 + ch * 8];
                bf[t] = *(const short8*)&Bs[(qc + t * 16 + lm) * 64 + ch * 8];
            }
#pragma unroll
            for (int i = 0; i < 4; ++i)
#pragma unroll
                for (int j = 0; j < 4; ++j)
                    acc[i][j] = MFMA(af[i], bf[j], acc[i][j], 0, 0, 0);
        }
        __syncthreads();
    }
    if (qkvP) {
#pragma unroll
        for (int i = 0; i < 4; ++i) {
            int mbase = m0 + qr + i * 16 + (lane >> 4) * 4;
            int bb = mbase / SEQ;
            int s0 = mbase - bb * SEQ;
#pragma unroll
            for (int j = 0; j < 4; ++j) {
                int n = n0 + qc + j * 16 + lm;
                float bs;
                if (n < 768) bs = bq[n] + qbias[n];
                else if (n < QKN) bs = bk[n - 768];
                else bs = bv[n - QKN] + vbias[n - QKN];
                if (n < QKN) {
#pragma unroll
                    for (int r = 0; r < 4; ++r)
                        qk[(size_t)(mbase + r) * QKN + n] = f2bf(acc[i][j][r] + bs);
                } else {
                    int c = n - QKN, h = c >> 6, d = c & 63;
                    ushort tmp[4];
#pragma unroll
                    for (int r = 0; r < 4; ++r) tmp[r] = f2bf(acc[i][j][r] + bs);
                    *(uint2*)&vT[(((size_t)bb * NH + h) * DH + d) * SEQ + s0] = *(uint2*)tmp;
                }
            }
        }
    } else {
#pragma unroll
        for (int i = 0; i < 4; ++i) {
            int mbase = m0 + qr + i * 16 + (lane >> 4) * 4;
#pragma unroll
            for (int j = 0; j < 4; ++j) {
                int n = n0 + qc + j * 16 + lm;
#pragma unroll
                for (int r = 0; r < 4; ++r) {
                    int row = mbase + r;
                    if (row < NPOS)
                        posKQ[(size_t)row * PN + n] = f2bf(acc[i][j][r]);
                }
            }
        }
    }
}

// ---------- 128x128-tile MFMA GEMM (output projection, 144 blocks) --------
__global__ __launch_bounds__(256) void gemm128x128(
    const ushort* __restrict__ A, const ushort* __restrict__ Bt,
    const float* __restrict__ bias, float* __restrict__ outF,
    int M, int N, int K)
{
    __shared__ ushort As[128 * 64];
    __shared__ ushort Bs[128 * 64];
    const int tid = threadIdx.x;
    const int lane = tid & 63, w = tid >> 6;
    const int n0 = blockIdx.x * 128, m0 = blockIdx.y * 128;
    const int lr = lane >> 3;
    const int lc = (lane & 7) ^ (lr & 7);
    const ushort* ga[4]; const ushort* gb[4];
#pragma unroll
    for (int p = 0; p < 4; ++p) {
        int row = (w * 4 + p) * 8 + lr;
        int arow = m0 + row; if (arow > M - 1) arow = M - 1;
        ga[p] = A + (size_t)arow * K + lc * 8;
        gb[p] = Bt + (size_t)(n0 + row) * K + lc * 8;
    }
    floatx4 acc[4][4] = {};
    const int qr = (w >> 1) * 64, qc = (w & 1) * 64;
    const int lm = lane & 15, lk = lane >> 4;
    for (int k0 = 0; k0 < K; k0 += 64) {
#pragma unroll
        for (int p = 0; p < 4; ++p) {
            gld16(ga[p], As + (w * 4 + p) * 512);
            gld16(gb[p], Bs + (w * 4 + p) * 512);
            ga[p] += 64; gb[p] += 64;
        }
        __syncthreads();
#pragma unroll
        for (int kk = 0; kk < 2; ++kk) {
            int ch = (kk * 4 + lk) ^ (lm & 7);
            short8 af[4], bf[4];
#pragma unroll
            for (int t = 0; t < 4; ++t) {
                af[t] = *(const short8*)&As[(qr + t * 16 + lm) * 64 + ch * 8];
                bf[t] = *(const short8*)&Bs[(qc + t * 16 + lm) * 64 + ch * 8];
            }
#pragma unroll
            for (int i = 0; i < 4; ++i)
#pragma unroll
                for (int j = 0; j < 4; ++j)
                    acc[i][j] = MFMA(af[i], bf[j], acc[i][j], 0, 0, 0);
        }
        __syncthreads();
    }
#pragma unroll
    for (int i = 0; i < 4; ++i) {
        int mbase = m0 + qr + i * 16 + (lane >> 4) * 4;
#pragma unroll
        for (int j = 0; j < 4; ++j) {
            int n = n0 + qc + j * 16 + lm;
            float bs = bias[n];
#pragma unroll
            for (int r = 0; r < 4; ++r) {
                int row = mbase + r;
                if (row < M) outF[(size_t)row * N + n] = acc[i][j][r] + bs;
            }
        }
    }
}

// ---------- fused attention v21: j-SPLIT (v19 body, 3 iters/block) --------
// grid (12, 12, 8) = 1152 blocks: x = i-tile(6) x jg(2); each block does
// j-tiles {3jg, 3jg+1, 3jg+2} and writes f32 PARTIAL (O, rowsum); combine
// kernel sums the two jg partials and divides. Mechanism: attn is bound by
// the per-block critical path (v14-v20: residency/barriers/L2/prefetch all
// ~null). L = dur*concurrent/total = 46us*512/576 ~ 41us/block. Halving
// the j-loop halves L (~22us); LDS 51KB -> 3 blocks/CU = 768 concurrent,
// 1152/768 = 1.5 rounds -> makespan ~33us vs 46. Iteration body is v19
// VERBATIM (measured best); only loop range, grid decode, and epilogue
// (store partials, no divide/shfl) change. VGPR <= 64 (v17 lesson);
// __expf (v18 lesson). t=767 overread lands in wsT pad.
__global__ __launch_bounds__(512, 2) void attn_part(
    const ushort* __restrict__ qk, const ushort* __restrict__ vT,
    const ushort* __restrict__ posKQ,
    float* __restrict__ pO, float* __restrict__ pR)
{
    __shared__ ushort kt[64 * 64];        // 8 KB  k tile (swizzled)
    __shared__ ushort kps[128 * 64];      // 16 KB Kp band (swizzled)
    __shared__ ushort cc[64 * 72];        // 9 KB  c2c scores (bf16)
    __shared__ ushort dqs[64 * 72];       // 9 KB  dq pre-shifted: [i][j]=dq[i][j-i+63]
    __shared__ ushort dks[64 * 72];       // 9 KB  dk pre-shifted: [i][j]=dk[j-i+63][j]
                                          // total 51.0 KB -> 3 blocks/CU

    const int tid = threadIdx.x;
    const int lane = tid & 63, w = tid >> 6;
    const int i0 = (blockIdx.x >> 1) * 64;
    const int jg = blockIdx.x & 1;
    const int h = blockIdx.y, b = blockIdx.z;
    const int lm = lane & 15, lq = lane >> 4;
    const int lr = lane >> 3, l8 = lane & 7;
    const int lc = l8 ^ (lr & 7);                 // swizzled source chunk

    // q fragments: register-resident (i-tile w>>1; two waves share a tile)
    short8 qf[2];
    {
        const ushort* qr = qk + (size_t)(b * SEQ + i0 + (w >> 1) * 16 + lm) * QKN + h * DH;
        qf[0] = *(const short8*)(qr + lq * 8);
        qf[1] = *(const short8*)(qr + 32 + lq * 8);
    }
    const ushort* kb = qk + 768 + h * DH;
    floatx4 occ[2] = {};
    float rs = 0.f;                               // rowsum for row tr*16+lm

    const int t0i = 320 - i0;
    const int tcb = (w & 1) * 4;
    const int tr = w >> 1;
    const int jbase = jg * 192;                   // this block's first j

    // stage first j-tile: kt + kps (DMA)
    {
        gld16(kb + (size_t)(b * SEQ + jbase + 8 * w + lr) * QKN + lc * 8, kt + w * 512);
        gld16(posKQ + (size_t)(t0i + jbase + 16 * w + lr) * PN + h * DH + lc * 8, kps + w * 1024);
        gld16(posKQ + (size_t)(t0i + jbase + 16 * w + 8 + lr) * PN + h * DH + lc * 8, kps + w * 1024 + 512);
    }

    for (int jt = 0; jt < 3; ++jt) {
        const int j0 = jbase + jt * 64;
        __syncthreads();        // (1) staging landed; prev softmax+PV reads done

        // JIT Qp fragment for dk (consumed last in B; latency hides under c2c+dq)
        short8 qpf[2];
        {
            const ushort* qpb = posKQ + (size_t)(t0i + j0 + w * 16 + lm) * PN
                                + 768 + h * DH + lq * 8;
            qpf[0] = *(const short8*)(qpb);
            qpf[1] = *(const short8*)(qpb + 32);
        }

        // ---- phase B: c2c + dq + dk -> bf16 buffers, unique writers ----
        { // c2c: i-tile w>>1 x j-tiles (w&1)*2+{0,1}
            int tjb = (w & 1) * 2;
            floatx4 a0 = {}, a1 = {};
#pragma unroll
            for (int kk = 0; kk < 2; ++kk) {
                int ch = (kk * 4 + lq) ^ (lm & 7);
                short8 b0 = *(const short8*)&kt[(tjb * 16 + lm) * 64 + ch * 8];
                short8 b1 = *(const short8*)&kt[((tjb + 1) * 16 + lm) * 64 + ch * 8];
                a0 = MFMA(qf[kk], b0, a0, 0, 0, 0);
                a1 = MFMA(qf[kk], b1, a1, 0, 0, 0);
            }
#pragma unroll
            for (int r = 0; r < 4; ++r) {
                cc[(tr * 16 + lq * 4 + r) * 72 + tjb * 16 + lm] = f2bf(a0[r]);
                cc[(tr * 16 + lq * 4 + r) * 72 + (tjb + 1) * 16 + lm] = f2bf(a1[r]);
            }
        }
        { // dq: i-tile w>>1 x t-tiles (tcb+{0..3}) from staged kps
            floatx4 d[4] = {};
#pragma unroll
            for (int kk = 0; kk < 2; ++kk) {
                int ch = (kk * 4 + lq) ^ (lm & 7);
#pragma unroll
                for (int s = 0; s < 4; ++s) {
                    short8 bf = *(const short8*)&kps[((tcb + s) * 16 + lm) * 64 + ch * 8];
                    d[s] = MFMA(qf[kk], bf, d[s], 0, 0, 0);
                }
            }
#pragma unroll
            for (int s = 0; s < 4; ++s) {
                int t = (tcb + s) * 16 + lm;
#pragma unroll
                for (int r = 0; r < 4; ++r) {
                    int i = tr * 16 + lq * 4 + r;
                    int j = t + i - 63;
                    if ((unsigned)j < 64u) dqs[i * 72 + j] = f2bf(d[s][r]);
                }
            }
        }
        { // dk: t-tile w x j-tiles {0..3}; A-operand = JIT qpf
            floatx4 e[4] = {};
#pragma unroll
            for (int kk = 0; kk < 2; ++kk) {
                int ch = (kk * 4 + lq) ^ (lm & 7);
#pragma unroll
                for (int s = 0; s < 4; ++s) {
                    short8 bf = *(const short8*)&kt[(s * 16 + lm) * 64 + ch * 8];
                    e[s] = MFMA(qpf[kk], bf, e[s], 0, 0, 0);
                }
            }
#pragma unroll
            for (int s = 0; s < 4; ++s) {
                int j = s * 16 + lm;
#pragma unroll
                for (int r = 0; r < 4; ++r) {
                    int t = w * 16 + lq * 4 + r;
                    int i = j - t + 63;
                    if ((unsigned)i < 64u) dks[i * 72 + j] = f2bf(e[s][r]);
                }
            }
        }
        __syncthreads();        // (2) B done; kt/kps free

        // issue next iter's staging (overlaps fused softmax+PV below)
        if (jt < 2) {
            int t0n = t0i + j0 + 64;
            gld16(kb + (size_t)(b * SEQ + j0 + 64 + 8 * w + lr) * QKN + lc * 8, kt + w * 512);
            gld16(posKQ + (size_t)(t0n + 16 * w + lr) * PN + h * DH + lc * 8, kps + w * 1024);
            gld16(posKQ + (size_t)(t0n + 16 * w + 8 + lr) * PN + h * DH + lc * 8, kps + w * 1024 + 512);
        }

        // ---- fused softmax + PV: P straight into A-fragments ----------
        {
            const int off = (tr * 16 + lm) * 72 + lq * 8;
            short8 af0, af1;
            float psum = 0.f;
            {
                uint4 c4 = *(const uint4*)&cc[off];
                uint4 q4 = *(const uint4*)&dqs[off];
                uint4 k4 = *(const uint4*)&dks[off];
                const ushort* cu = (const ushort*)&c4;
                const ushort* qu = (const ushort*)&q4;
                const ushort* ku = (const ushort*)&k4;
                ushort pv[8];
#pragma unroll
                for (int c = 0; c < 8; ++c) {
                    float pe = __expf((bf2f(cu[c]) + bf2f(qu[c]) + bf2f(ku[c])) * 0.125f);
                    psum += pe;
                    pv[c] = f2bf(pe);
                }
                af0 = *(const short8*)pv;
            }
            {
                uint4 c4 = *(const uint4*)&cc[off + 32];
                uint4 q4 = *(const uint4*)&dqs[off + 32];
                uint4 k4 = *(const uint4*)&dks[off + 32];
                const ushort* cu = (const ushort*)&c4;
                const ushort* qu = (const ushort*)&q4;
                const ushort* ku = (const ushort*)&k4;
                ushort pv[8];
#pragma unroll
                for (int c = 0; c < 8; ++c) {
                    float pe = __expf((bf2f(cu[c]) + bf2f(qu[c]) + bf2f(ku[c])) * 0.125f);
                    psum += pe;
                    pv[c] = f2bf(pe);
                }
                af1 = *(const short8*)pv;
            }
            // row total across the 4 lanes (lq) sharing this row
            psum += __shfl_xor(psum, 16);
            psum += __shfl_xor(psum, 32);
            rs += psum;

            int dtb = (w & 1) * 2;
#pragma unroll
            for (int t2 = 0; t2 < 2; ++t2) {
                int dt = dtb + t2;
                const ushort* vr = vT + ((size_t)(b * NH + h) * DH + dt * 16 + lm) * SEQ + j0;
                short8 vf0 = *(const short8*)(vr + lq * 8);
                short8 vf1 = *(const short8*)(vr + 32 + lq * 8);
                occ[t2] = MFMA(af0, vf0, occ[t2], 0, 0, 0);
                occ[t2] = MFMA(af1, vf1, occ[t2], 0, 0, 0);
            }
        }
        // no barrier: next iter's (1) orders these reads before next B's writes
    }

    // epilogue: f32 partials (unique (row, d-col) per wave; rs once per row)
    {
        int dtb = (w & 1) * 2;
#pragma unroll
        for (int t2 = 0; t2 < 2; ++t2) {
#pragma unroll
            for (int r = 0; r < 4; ++r) {
                int row = tr * 16 + lq * 4 + r;
                pO[((size_t)jg * NTOK + b * SEQ + i0 + row) * DIM + h * DH + (dtb + t2) * 16 + lm]
                    = occ[t2][r];
            }
        }
        if ((w & 1) == 0 && lq == 0)
            pR[((size_t)jg * NTOK + b * SEQ + i0 + tr * 16 + lm) * NH + h] = rs;
    }
}

// ---------- combine: aob = (pO[0] + pO[1]) / (pR[0] + pR[1]) --------------
__global__ __launch_bounds__(256) void combine(
    const float* __restrict__ pO, const float* __restrict__ pR,
    ushort* __restrict__ aob)
{
    const int n4 = NTOK * DIM / 4;                 // 589824
    int idx = blockIdx.x * 256 + threadIdx.x;      // grid exactly n4/256
    int e0 = idx * 4;
    int row = e0 / DIM;
    int h = (e0 - row * DIM) >> 6;
    float4 a = ((const float4*)pO)[idx];
    float4 c = ((const float4*)pO)[idx + n4];
    float r = pR[row * NH + h] + pR[(NTOK + row) * NH + h];
    float inv = 1.0f / r;
    ushort o[4] = { f2bf((a.x + c.x) * inv), f2bf((a.y + c.y) * inv),
                    f2bf((a.z + c.z) * inv), f2bf((a.w + c.w) * inv) };
    ((uint2*)aob)[idx] = *(uint2*)o;
}

extern "C" void kernel_launch(void* const* d_in, const int* in_sizes, int n_in,
                              void* d_out, int out_size, void* d_ws, size_t ws_size,
                              hipStream_t stream) {
    const float* x   = (const float*)d_in[0];
    const float* rpe = (const float*)d_in[1];
    const float* Wq  = (const float*)d_in[2];
    const float* bq  = (const float*)d_in[3];
    const float* Wk  = (const float*)d_in[4];
    const float* bk  = (const float*)d_in[5];
    const float* Wv  = (const float*)d_in[6];
    const float* bv  = (const float*)d_in[7];
    const float* qbias = (const float*)d_in[8];
    const float* vbias = (const float*)d_in[9];
    const float* Wpk = (const float*)d_in[10];
    const float* Wpq = (const float*)d_in[11];
    const float* Wo  = (const float*)d_in[12];
    const float* bo  = (const float*)d_in[13];
    float* out = (float*)d_out;

    char* ws = (char*)d_ws;
    ushort* xb    = (ushort*)ws; ws += (size_t)NTOK * DIM * 2;
    ushort* qkbuf = (ushort*)ws; ws += (size_t)NTOK * QKN * 2;
    ushort* vT    = (ushort*)ws; ws += (size_t)NTOK * DIM * 2;
    ushort* aob   = (ushort*)ws; ws += (size_t)NTOK * DIM * 2;
    ushort* rpeb  = (ushort*)ws; ws += (size_t)NPOS * DIM * 2;
    ushort* posKQ = (ushort*)ws; ws += (size_t)NPOS * PN * 2;
    ushort* wsT   = (ushort*)ws; ws += (size_t)6 * DIM * DIM * 2;   // must follow posKQ (t=767 overread pad)
    float*  pO    = (float*)ws;  ws += (size_t)2 * NTOK * DIM * 4;  // j-split partials
    float*  pR    = (float*)ws;  ws += (size_t)2 * NTOK * NH * 4;

    // 1) converts + weight transposes
    prep<<<dim3(12, 12, 7), dim3(256), 0, stream>>>(
        Wq, Wk, Wv, Wpk, Wpq, Wo, x, rpe, wsT, xb, rpeb);
    // 2) QKV projection + positional projections in one launch (504 blocks)
    proj_all<<<dim3(504), dim3(256), 0, stream>>>(
        xb, rpeb, wsT, bq, qbias, bk, bv, vbias, qkbuf, vT, posKQ);
    // 3) fused attention, j-split into 2 half-length blocks (1152 blocks)
    attn_part<<<dim3(12, NH, BATCH), dim3(512), 0, stream>>>(
        qkbuf, vT, posKQ, pO, pR);
    // 3b) combine partials -> aob (2304 blocks, ~23MB)
    combine<<<dim3(NTOK * DIM / 4 / 256), dim3(256), 0, stream>>>(pO, pR, aob);
    // 4) output projection -> fp32 d_out (144 blocks, 128x128 tiles)
    gemm128x128<<<dim3(DIM / 128, NTOK / 128), dim3(256), 0, stream>>>(
        aob, wsT + (size_t)5 * DIM * DIM, bo, out, NTOK, DIM, DIM);
}

// Round 14
// 180.611 us; speedup vs baseline: 1.0932x; 1.0932x over previous
//
#include <hip/hip_runtime.h>
#include <hip/hip_bf16.h>
#include <math.h>

#define BATCH 8
#define SEQ 384
#define DIM 768
#define NH 12
#define DH 64
#define NPOS 767
#define POS_OFF 128
#define NTOK (BATCH * SEQ)
#define QKN 1536
#define QKVN 2304
#define PN 1536

typedef __attribute__((ext_vector_type(8))) short short8;
typedef __attribute__((ext_vector_type(4))) float floatx4;
typedef unsigned int u32;

__device__ __forceinline__ ushort f2bf(float f) {
    __hip_bfloat16 h = __float2bfloat16(f);
    return *reinterpret_cast<ushort*>(&h);
}
__device__ __forceinline__ float bf2f(ushort u) {
    u32 x = ((u32)u) << 16;
    float f; __builtin_memcpy(&f, &x, 4); return f;
}

// async global->LDS, 16B per lane; lds dest = wave-uniform base + lane*16
__device__ __forceinline__ void gld16(const ushort* g, ushort* l) {
    __builtin_amdgcn_global_load_lds(
        (const __attribute__((address_space(1))) u32*)g,
        (__attribute__((address_space(3))) u32*)l, 16, 0, 0);
}

#define MFMA __builtin_amdgcn_mfma_f32_16x16x32_bf16

// ---------- prep: weight transposes (z<6) + row converts (z==6) -----------
__global__ __launch_bounds__(256) void prep(
    const float* W0, const float* W1, const float* W2,
    const float* W3, const float* W4, const float* W5,
    const float* x, const float* rpe,
    ushort* __restrict__ wsT, ushort* __restrict__ xb, ushort* __restrict__ rpeb)
{
    const int tid = threadIdx.x;
    if (blockIdx.z < 6) {
        __shared__ float t[64][65];
        const float* srcs[6] = {W0, W1, W2, W3, W4, W5};
        const float* in = srcs[blockIdx.z];
        ushort* out = wsT + (size_t)blockIdx.z * DIM * DIM;
        const int r0 = blockIdx.y * 64, c0 = blockIdx.x * 64;
        for (int p = 0; p < 16; ++p) {
            int e = tid + p * 256, i = e >> 6, j = e & 63;
            t[i][j] = in[(size_t)(r0 + i) * DIM + c0 + j];
        }
        __syncthreads();
        for (int p = 0; p < 16; ++p) {
            int e = tid + p * 256, i = e >> 6, j = e & 63;
            out[(size_t)(c0 + i) * DIM + r0 + j] = f2bf(t[j][i]);
        }
    } else {
        const int n4x = NTOK * DIM / 4;
        const int n4p = NPOS * DIM / 4;
        const int fb = blockIdx.y * 12 + blockIdx.x;      // 0..143
        for (int idx = fb * 256 + tid; idx < n4x + n4p; idx += 144 * 256) {
            const float* src; ushort* dst; int j;
            if (idx < n4x) { src = x; dst = xb; j = idx; }
            else { src = rpe + (size_t)POS_OFF * DIM; dst = rpeb; j = idx - n4x; }
            float4 f = ((const float4*)src)[j];
            ushort o[4] = {f2bf(f.x), f2bf(f.y), f2bf(f.z), f2bf(f.w)};
            *(uint2*)&dst[(size_t)j * 4] = *(uint2*)o;
        }
    }
}

// ---------- combined projections: QKV (blocks 0..431) + pos (432..503) ----
__global__ __launch_bounds__(256) void proj_all(
    const ushort* __restrict__ xb, const ushort* __restrict__ rpeb,
    const ushort* __restrict__ wsT,
    const float* __restrict__ bq, const float* __restrict__ qbias,
    const float* __restrict__ bk, const float* __restrict__ bv,
    const float* __restrict__ vbias,
    ushort* __restrict__ qk, ushort* __restrict__ vT, ushort* __restrict__ posKQ)
{
    __shared__ ushort As[128 * 64];
    __shared__ ushort Bs[128 * 64];
    const int tid = threadIdx.x;
    const int lane = tid & 63, w = tid >> 6;
    const int id = blockIdx.x;
    const bool qkvP = id < 432;
    const ushort* A; const ushort* Bt; int m0, n0, M;
    if (qkvP) {
        m0 = (id % 24) * 128; n0 = (id / 24) * 128;
        A = xb; Bt = wsT; M = NTOK;
    } else {
        int p = id - 432;
        m0 = (p % 6) * 128; n0 = (p / 6) * 128;
        A = rpeb; Bt = wsT + (size_t)3 * DIM * DIM; M = NPOS;
    }
    const int lr = lane >> 3;
    const int lc = (lane & 7) ^ (lr & 7);
    const ushort* ga[4]; const ushort* gb[4];
#pragma unroll
    for (int p = 0; p < 4; ++p) {
        int row = (w * 4 + p) * 8 + lr;
        int arow = m0 + row; if (arow > M - 1) arow = M - 1;
        ga[p] = A + (size_t)arow * DIM + lc * 8;
        gb[p] = Bt + (size_t)(n0 + row) * DIM + lc * 8;
    }
    floatx4 acc[4][4] = {};
    const int qr = (w >> 1) * 64, qc = (w & 1) * 64;
    const int lm = lane & 15, lk = lane >> 4;
    for (int k0 = 0; k0 < DIM; k0 += 64) {
#pragma unroll
        for (int p = 0; p < 4; ++p) {
            gld16(ga[p], As + (w * 4 + p) * 512);
            gld16(gb[p], Bs + (w * 4 + p) * 512);
            ga[p] += 64; gb[p] += 64;
        }
        __syncthreads();
#pragma unroll
        for (int kk = 0; kk < 2; ++kk) {
            int ch = (kk * 4 + lk) ^ (lm & 7);
            short8 af[4], bf[4];
#pragma unroll
            for (int t = 0; t < 4; ++t) {
                af[t] = *(const short8*)&As[(qr + t * 16 + lm) * 64 + ch * 8];
                bf[t] = *(const short8*)&Bs[(qc + t * 16 + lm) * 64 + ch * 8];
            }
#pragma unroll
            for (int i = 0; i < 4; ++i)
#pragma unroll
                for (int j = 0; j < 4; ++j)
                    acc[i][j] = MFMA(af[i], bf[j], acc[i][j], 0, 0, 0);
        }
        __syncthreads();
    }
    if (qkvP) {
#pragma unroll
        for (int i = 0; i < 4; ++i) {
            int mbase = m0 + qr + i * 16 + (lane >> 4) * 4;
            int bb = mbase / SEQ;
            int s0 = mbase - bb * SEQ;
#pragma unroll
            for (int j = 0; j < 4; ++j) {
                int n = n0 + qc + j * 16 + lm;
                float bs;
                if (n < 768) bs = bq[n] + qbias[n];
                else if (n < QKN) bs = bk[n - 768];
                else bs = bv[n - QKN] + vbias[n - QKN];
                if (n < QKN) {
#pragma unroll
                    for (int r = 0; r < 4; ++r)
                        qk[(size_t)(mbase + r) * QKN + n] = f2bf(acc[i][j][r] + bs);
                } else {
                    int c = n - QKN, h = c >> 6, d = c & 63;
                    ushort tmp[4];
#pragma unroll
                    for (int r = 0; r < 4; ++r) tmp[r] = f2bf(acc[i][j][r] + bs);
                    *(uint2*)&vT[(((size_t)bb * NH + h) * DH + d) * SEQ + s0] = *(uint2*)tmp;
                }
            }
        }
    } else {
#pragma unroll
        for (int i = 0; i < 4; ++i) {
            int mbase = m0 + qr + i * 16 + (lane >> 4) * 4;
#pragma unroll
            for (int j = 0; j < 4; ++j) {
                int n = n0 + qc + j * 16 + lm;
#pragma unroll
                for (int r = 0; r < 4; ++r) {
                    int row = mbase + r;
                    if (row < NPOS)
                        posKQ[(size_t)row * PN + n] = f2bf(acc[i][j][r]);
                }
            }
        }
    }
}

// ---------- 128x64-tile MFMA GEMM (output projection, 288 blocks) ---------
// Kept from the best-total run (v14, 180.7us): gemm128x128 showed no
// measurable advantage (non-attn residuals 134-141 vs 132-136).
__global__ __launch_bounds__(256) void gemm128x64(
    const ushort* __restrict__ A, const ushort* __restrict__ Bt,
    const float* __restrict__ bias, float* __restrict__ outF,
    int M, int N, int K)
{
    __shared__ ushort As[128 * 64];
    __shared__ ushort Bs[64 * 64];
    const int tid = threadIdx.x;
    const int lane = tid & 63, w = tid >> 6;
    const int n0 = blockIdx.x * 64, m0 = blockIdx.y * 128;
    const int lr = lane >> 3;
    const int lc = (lane & 7) ^ (lr & 7);
    const ushort* ga[4]; const ushort* gb[2];
#pragma unroll
    for (int p = 0; p < 4; ++p) {
        int arow = m0 + (w * 4 + p) * 8 + lr; if (arow > M - 1) arow = M - 1;
        ga[p] = A + (size_t)arow * K + lc * 8;
    }
#pragma unroll
    for (int p = 0; p < 2; ++p)
        gb[p] = Bt + (size_t)(n0 + (w * 2 + p) * 8 + lr) * K + lc * 8;
    floatx4 acc[4][2] = {};
    const int qr = (w >> 1) * 64, qc = (w & 1) * 32;
    const int lm = lane & 15, lk = lane >> 4;
    for (int k0 = 0; k0 < K; k0 += 64) {
#pragma unroll
        for (int p = 0; p < 4; ++p) { gld16(ga[p], As + (w * 4 + p) * 512); ga[p] += 64; }
#pragma unroll
        for (int p = 0; p < 2; ++p) { gld16(gb[p], Bs + (w * 2 + p) * 512); gb[p] += 64; }
        __syncthreads();
#pragma unroll
        for (int kk = 0; kk < 2; ++kk) {
            int ch = (kk * 4 + lk) ^ (lm & 7);
            short8 af[4], bf[2];
#pragma unroll
            for (int t = 0; t < 4; ++t)
                af[t] = *(const short8*)&As[(qr + t * 16 + lm) * 64 + ch * 8];
#pragma unroll
            for (int t = 0; t < 2; ++t)
                bf[t] = *(const short8*)&Bs[(qc + t * 16 + lm) * 64 + ch * 8];
#pragma unroll
            for (int i = 0; i < 4; ++i)
#pragma unroll
                for (int j = 0; j < 2; ++j)
                    acc[i][j] = MFMA(af[i], bf[j], acc[i][j], 0, 0, 0);
        }
        __syncthreads();
    }
#pragma unroll
    for (int i = 0; i < 4; ++i) {
        int mbase = m0 + qr + i * 16 + (lane >> 4) * 4;
#pragma unroll
        for (int j = 0; j < 2; ++j) {
            int n = n0 + qc + j * 16 + lm;
            float bs = bias[n];
#pragma unroll
            for (int r = 0; r < 4; ++r) {
                int row = mbase + r;
                if (row < M) outF[(size_t)row * N + n] = acc[i][j][r] + bs;
            }
        }
    }
}

// ---------- fused attention v22 = v20 verbatim (best measured, 45.7us) ----
// grid (6, 12, 8), 512 threads (8 waves). LDS 67.0KB, 2 blocks/CU.
// Measured-best composition after 13 structural experiments: staged kt/kps
// DMA + vT DMA-staged dbuf (v20, -2us), register softmax 2 barriers/iter
// (v15), JIT qpf, __expf only (v18 lesson: exp2f = ocml path, +9us),
// no reg cap (v9-v12: caps spill), no XCD swizzle / no j-split (v16/v21:
// net-negative). Falsified levers: residency (v14), barrier count (v15),
// L2 locality (v16), reg prefetch (v17: 64-VGPR occupancy cliff),
// work-split (v21: ~18us/block fixed cost + partial traffic).
// t=767 overread (i0=0, jt=5) lands in wsT pad; outputs band-masked.
__global__ __launch_bounds__(512, 2) void attn_fused22(
    const ushort* __restrict__ qk, const ushort* __restrict__ vT,
    const ushort* __restrict__ posKQ, ushort* __restrict__ aob)
{
    __shared__ ushort kt[64 * 64];        // 8 KB  k tile (swizzled)
    __shared__ ushort kps[128 * 64];      // 16 KB Kp band (swizzled)
    __shared__ ushort vts[2][64 * 64];    // 16 KB v tile (swizzled), dbuf
    __shared__ ushort cc[64 * 72];        // 9 KB  c2c scores (bf16)
    __shared__ ushort dqs[64 * 72];       // 9 KB  dq pre-shifted: [i][j]=dq[i][j-i+63]
    __shared__ ushort dks[64 * 72];       // 9 KB  dk pre-shifted: [i][j]=dk[j-i+63][j]
                                          // total 67.0 KB

    const int tid = threadIdx.x;
    const int lane = tid & 63, w = tid >> 6;
    const int i0 = blockIdx.x * 64;
    const int h = blockIdx.y, b = blockIdx.z;
    const int lm = lane & 15, lq = lane >> 4;
    const int lr = lane >> 3, l8 = lane & 7;
    const int lc = l8 ^ (lr & 7);                 // swizzled source chunk

    // q fragments: register-resident (i-tile w>>1; two waves share a tile)
    short8 qf[2];
    {
        const ushort* qr = qk + (size_t)(b * SEQ + i0 + (w >> 1) * 16 + lm) * QKN + h * DH;
        qf[0] = *(const short8*)(qr + lq * 8);
        qf[1] = *(const short8*)(qr + 32 + lq * 8);
    }
    const ushort* kb = qk + 768 + h * DH;
    const ushort* vTb = vT + (size_t)(b * NH + h) * DH * SEQ;   // row d, col s
    floatx4 occ[2] = {};
    float rs = 0.f;                               // rowsum for row tr*16+lm

    const int t0i = 320 - i0;
    const int tcb = (w & 1) * 4;
    const int tr = w >> 1;

    // stage j-tile 0: kt + kps + vts[0] (DMA)
    {
        gld16(kb + (size_t)(b * SEQ + 8 * w + lr) * QKN + lc * 8, kt + w * 512);
        gld16(posKQ + (size_t)(t0i + 16 * w + lr) * PN + h * DH + lc * 8, kps + w * 1024);
        gld16(posKQ + (size_t)(t0i + 16 * w + 8 + lr) * PN + h * DH + lc * 8, kps + w * 1024 + 512);
        gld16(vTb + (size_t)(8 * w + lr) * SEQ + lc * 8, vts[0] + w * 512);
    }

    for (int jt = 0; jt < 6; ++jt) {
        const int j0 = jt * 64;
        const int cur = jt & 1;
        __syncthreads();        // (1) staging landed; prev softmax+PV reads done

        // JIT Qp fragment for dk (consumed last in B; latency hides under c2c+dq)
        short8 qpf[2];
        {
            const ushort* qpb = posKQ + (size_t)(t0i + j0 + w * 16 + lm) * PN
                                + 768 + h * DH + lq * 8;
            qpf[0] = *(const short8*)(qpb);
            qpf[1] = *(const short8*)(qpb + 32);
        }

        // ---- phase B: c2c + dq + dk -> bf16 buffers, unique writers ----
        { // c2c: i-tile w>>1 x j-tiles (w&1)*2+{0,1}
            int tjb = (w & 1) * 2;
            floatx4 a0 = {}, a1 = {};
#pragma unroll
            for (int kk = 0; kk < 2; ++kk) {
                int ch = (kk * 4 + lq) ^ (lm & 7);
                short8 b0 = *(const short8*)&kt[(tjb * 16 + lm) * 64 + ch * 8];
                short8 b1 = *(const short8*)&kt[((tjb + 1) * 16 + lm) * 64 + ch * 8];
                a0 = MFMA(qf[kk], b0, a0, 0, 0, 0);
                a1 = MFMA(qf[kk], b1, a1, 0, 0, 0);
            }
#pragma unroll
            for (int r = 0; r < 4; ++r) {
                cc[(tr * 16 + lq * 4 + r) * 72 + tjb * 16 + lm] = f2bf(a0[r]);
                cc[(tr * 16 + lq * 4 + r) * 72 + (tjb + 1) * 16 + lm] = f2bf(a1[r]);
            }
        }
        { // dq: i-tile w>>1 x t-tiles (tcb+{0..3}) from staged kps
            floatx4 d[4] = {};
#pragma unroll
            for (int kk = 0; kk < 2; ++kk) {
                int ch = (kk * 4 + lq) ^ (lm & 7);
#pragma unroll
                for (int s = 0; s < 4; ++s) {
                    short8 bf = *(const short8*)&kps[((tcb + s) * 16 + lm) * 64 + ch * 8];
                    d[s] = MFMA(qf[kk], bf, d[s], 0, 0, 0);
                }
            }
#pragma unroll
            for (int s = 0; s < 4; ++s) {
                int t = (tcb + s) * 16 + lm;
#pragma unroll
                for (int r = 0; r < 4; ++r) {
                    int i = tr * 16 + lq * 4 + r;
                    int j = t + i - 63;
                    if ((unsigned)j < 64u) dqs[i * 72 + j] = f2bf(d[s][r]);
                }
            }
        }
        { // dk: t-tile w x j-tiles {0..3}; A-operand = JIT qpf
            floatx4 e[4] = {};
#pragma unroll
            for (int kk = 0; kk < 2; ++kk) {
                int ch = (kk * 4 + lq) ^ (lm & 7);
#pragma unroll
                for (int s = 0; s < 4; ++s) {
                    short8 bf = *(const short8*)&kt[(s * 16 + lm) * 64 + ch * 8];
                    e[s] = MFMA(qpf[kk], bf, e[s], 0, 0, 0);
                }
            }
#pragma unroll
            for (int s = 0; s < 4; ++s) {
                int j = s * 16 + lm;
#pragma unroll
                for (int r = 0; r < 4; ++r) {
                    int t = w * 16 + lq * 4 + r;
                    int i = j - t + 63;
                    if ((unsigned)i < 64u) dks[i * 72 + j] = f2bf(e[s][r]);
                }
            }
        }
        __syncthreads();        // (2) B done; kt/kps free

        // issue next iter's staging (kt/kps + vts[other]); overlaps softmax+PV
        if (jt < 5) {
            int t0n = t0i + j0 + 64;
            gld16(kb + (size_t)(b * SEQ + j0 + 64 + 8 * w + lr) * QKN + lc * 8, kt + w * 512);
            gld16(posKQ + (size_t)(t0n + 16 * w + lr) * PN + h * DH + lc * 8, kps + w * 1024);
            gld16(posKQ + (size_t)(t0n + 16 * w + 8 + lr) * PN + h * DH + lc * 8, kps + w * 1024 + 512);
            gld16(vTb + (size_t)(8 * w + lr) * SEQ + j0 + 64 + lc * 8, vts[cur ^ 1] + w * 512);
        }

        // ---- fused softmax + PV: P straight into A-fragments ----------
        {
            const int off = (tr * 16 + lm) * 72 + lq * 8;
            short8 af0, af1;
            float psum = 0.f;
            {
                uint4 c4 = *(const uint4*)&cc[off];
                uint4 q4 = *(const uint4*)&dqs[off];
                uint4 k4 = *(const uint4*)&dks[off];
                const ushort* cu = (const ushort*)&c4;
                const ushort* qu = (const ushort*)&q4;
                const ushort* ku = (const ushort*)&k4;
                ushort pv[8];
#pragma unroll
                for (int c = 0; c < 8; ++c) {
                    float pe = __expf((bf2f(cu[c]) + bf2f(qu[c]) + bf2f(ku[c])) * 0.125f);
                    psum += pe;
                    pv[c] = f2bf(pe);
                }
                af0 = *(const short8*)pv;
            }
            {
                uint4 c4 = *(const uint4*)&cc[off + 32];
                uint4 q4 = *(const uint4*)&dqs[off + 32];
                uint4 k4 = *(const uint4*)&dks[off + 32];
                const ushort* cu = (const ushort*)&c4;
                const ushort* qu = (const ushort*)&q4;
                const ushort* ku = (const ushort*)&k4;
                ushort pv[8];
#pragma unroll
                for (int c = 0; c < 8; ++c) {
                    float pe = __expf((bf2f(cu[c]) + bf2f(qu[c]) + bf2f(ku[c])) * 0.125f);
                    psum += pe;
                    pv[c] = f2bf(pe);
                }
                af1 = *(const short8*)pv;
            }
            // row total across the 4 lanes (lq) sharing this row
            psum += __shfl_xor(psum, 16);
            psum += __shfl_xor(psum, 32);
            rs += psum;

            int dtb = (w & 1) * 2;
#pragma unroll
            for (int t2 = 0; t2 < 2; ++t2) {
                int dt = dtb + t2;
                short8 vf0 = *(const short8*)&vts[cur][(dt * 16 + lm) * 64 + ((lq) ^ (lm & 7)) * 8];
                short8 vf1 = *(const short8*)&vts[cur][(dt * 16 + lm) * 64 + ((4 + lq) ^ (lm & 7)) * 8];
                occ[t2] = MFMA(af0, vf0, occ[t2], 0, 0, 0);
                occ[t2] = MFMA(af1, vf1, occ[t2], 0, 0, 0);
            }
        }
        // no barrier: next iter's (1) orders these reads before next B's writes
    }

    {
        int dtb = (w & 1) * 2;
#pragma unroll
        for (int t2 = 0; t2 < 2; ++t2) {
#pragma unroll
            for (int r = 0; r < 4; ++r) {
                int row = tr * 16 + lq * 4 + r;
                float rsv = __shfl(rs, lq * 4 + r);   // lane lq*4+r holds row's sum
                float ov = occ[t2][r] / rsv;
                aob[(size_t)(b * SEQ + i0 + row) * DIM + h * DH + (dtb + t2) * 16 + lm] = f2bf(ov);
            }
        }
    }
}

extern "C" void kernel_launch(void* const* d_in, const int* in_sizes, int n_in,
                              void* d_out, int out_size, void* d_ws, size_t ws_size,
                              hipStream_t stream) {
    const float* x   = (const float*)d_in[0];
    const float* rpe = (const float*)d_in[1];
    const float* Wq  = (const float*)d_in[2];
    const float* bq  = (const float*)d_in[3];
    const float* Wk  = (const float*)d_in[4];
    const float* bk  = (const float*)d_in[5];
    const float* Wv  = (const float*)d_in[6];
    const float* bv  = (const float*)d_in[7];
    const float* qbias = (const float*)d_in[8];
    const float* vbias = (const float*)d_in[9];
    const float* Wpk = (const float*)d_in[10];
    const float* Wpq = (const float*)d_in[11];
    const float* Wo  = (const float*)d_in[12];
    const float* bo  = (const float*)d_in[13];
    float* out = (float*)d_out;

    char* ws = (char*)d_ws;
    ushort* xb    = (ushort*)ws; ws += (size_t)NTOK * DIM * 2;
    ushort* qkbuf = (ushort*)ws; ws += (size_t)NTOK * QKN * 2;
    ushort* vT    = (ushort*)ws; ws += (size_t)NTOK * DIM * 2;
    ushort* aob   = (ushort*)ws; ws += (size_t)NTOK * DIM * 2;
    ushort* rpeb  = (ushort*)ws; ws += (size_t)NPOS * DIM * 2;
    ushort* posKQ = (ushort*)ws; ws += (size_t)NPOS * PN * 2;
    ushort* wsT   = (ushort*)ws; ws += (size_t)6 * DIM * DIM * 2;   // must follow posKQ (t=767 overread pad)

    // 1) converts + weight transposes
    prep<<<dim3(12, 12, 7), dim3(256), 0, stream>>>(
        Wq, Wk, Wv, Wpk, Wpq, Wo, x, rpe, wsT, xb, rpeb);
    // 2) QKV projection + positional projections in one launch (504 blocks)
    proj_all<<<dim3(504), dim3(256), 0, stream>>>(
        xb, rpeb, wsT, bq, qbias, bk, bv, vbias, qkbuf, vT, posKQ);
    // 3) fused attention v22 (= v20, measured best attn: 45.7-47.1us)
    attn_fused22<<<dim3(SEQ / 64, NH, BATCH), dim3(512), 0, stream>>>(qkbuf, vT, posKQ, aob);
    // 4) output projection -> fp32 d_out (288 blocks, from best-total run)
    gemm128x64<<<dim3(DIM / 64, NTOK / 128), dim3(256), 0, stream>>>(
        aob, wsT + (size_t)5 * DIM * DIM, bo, out, NTOK, DIM, DIM);
}